// Round 1
// baseline (29215.152 us; speedup 1.0000x reference)
//
#include <hip/hip_runtime.h>
#include <math.h>

typedef unsigned short u16;
typedef __attribute__((ext_vector_type(8))) short short8;
typedef __attribute__((ext_vector_type(4))) float float4v;

#define HH   512
#define BB   256
#define TLEN 512
#define DD   64

__device__ __forceinline__ float sigm(float x) { return 1.0f / (1.0f + __expf(-x)); }

__device__ __forceinline__ u16 bf16rn(float v) {
    unsigned u = __float_as_uint(v);
    u += 0x7fffu + ((u >> 16) & 1u);
    return (u16)(u >> 16);
}
__device__ __forceinline__ float bf16tf(u16 h) { return __uint_as_float(((unsigned)h) << 16); }

// ---------------- precompute kernels ----------------

__global__ __launch_bounds__(256) void split_kernel(const float* __restrict__ src,
                                                    u16* __restrict__ hi, u16* __restrict__ lo, int n)
{
    for (int i = blockIdx.x * 256 + threadIdx.x; i < n; i += gridDim.x * 256) {
        float v = src[i];
        u16 h = bf16rn(v);
        hi[i] = h;
        lo[i] = bf16rn(v - bf16tf(h));
    }
}

__global__ __launch_bounds__(256) void zero_kernel(unsigned* p, int n)
{
    int i = blockIdx.x * 256 + threadIdx.x;
    if (i < n) p[i] = 0u;
}

// ---------------- persistent fused LSTM (both layers, pipelined over t) ----------------
// One launch. Time loop inside; 4 independent m-group barriers (idx&3).
// The computation is fully batch-parallel: a block only touches batch rows
// [m0, m0+64) for A-reads / c / h / h1last, so groups never interact.
// Per group: 32 layer-0 blocks + 32 layer-1 blocks = 64 arrivals.
// Iteration n: layer0 computes step t=n (skip n==512), layer1 step t=n-1 (skip n==0).
// Inner chunk loop / MFMA structure / hi-lo bf16 split identical to the proven
// per-launch kernel (absmax 7.6e-6).
__global__ __launch_bounds__(256) void lstm_persistent(
    const u16* __restrict__ xhi, const u16* __restrict__ xlo,
    const u16* __restrict__ Wih0h, const u16* __restrict__ Wih0l,
    const u16* __restrict__ Whh0h, const u16* __restrict__ Whh0l,
    const u16* __restrict__ Wih1h, const u16* __restrict__ Wih1l,
    const u16* __restrict__ Whh1h, const u16* __restrict__ Whh1l,
    const float* __restrict__ bi0, const float* __restrict__ bh0,
    const float* __restrict__ bi1, const float* __restrict__ bh1,
    u16* h0hA, u16* h0lA, u16* h0hB, u16* h0lB,   // h0 parity-0 / parity-1 buffers
    u16* h1hA, u16* h1lA, u16* h1hB, u16* h1lB,   // h1 parity-0 / parity-1 buffers
    float* __restrict__ c0, float* __restrict__ c1,
    float* __restrict__ h1last, unsigned* bar)
{
    __shared__ u16 sBh[2][2048]; // [buf][64 gate-rows x 32 k]
    __shared__ u16 sBl[2][2048];

    const int tid  = threadIdx.x;
    const int lane = tid & 63;
    const int wv   = tid >> 6;
    const bool role1 = (blockIdx.x >= 128);
    const int idx = blockIdx.x & 127;
    const int m0  = (idx & 3) * 64;
    const int j0  = (idx >> 2) * 16;
    const int gid = idx & 3;
    unsigned* bcnt = bar + gid * 64;       // count / gen in separate 128B lines
    unsigned* bgen = bar + gid * 64 + 32;

    // role-invariant config
    const u16 *B1h, *B1l, *B2h, *B2l;
    int ld1, C1, C, ldb1;
    if (!role1) {
        ld1 = TLEN * DD; C1 = 2;
        B1h = Wih0h; B1l = Wih0l; ldb1 = DD;
        B2h = Whh0h; B2l = Whh0l;
        C = 18;                      // 64/32 + 512/32
    } else {
        ld1 = HH; C1 = 16;
        B1h = Wih1h; B1l = Wih1l; ldb1 = HH;
        B2h = Whh1h; B2l = Whh1l;
        C = 32;                      // 512/32 + 512/32
    }

    // B staging: thread -> gate-row r=tid>>2 (g=r>>4, j=r&15), ksub=(tid&3)*8
    const int br   = tid >> 2;
    const int grow = (br >> 4) * HH + j0 + (br & 15);
    const int bks  = (tid & 3) * 8;
    // A fragment: row = m0 + wv*16 + (lane&15), k-offset (lane>>4)*8
    const int arow = m0 + wv * 16 + (lane & 15);
    const int akq  = (lane >> 4) * 8;
    const int fo   = (lane & 15) * 32 + akq; // frag offset within a 16-row gate tile

    // epilogue constants (time-invariant): biases loaded once
    const float* pbi = role1 ? bi1 : bi0;
    const float* pbh = role1 ? bh1 : bh0;
    float* cc = role1 ? c1 : c0;
    const int jj = j0 + (lane & 15);
    const float bI = pbi[jj] + pbh[jj];
    const float bF = pbi[HH + jj] + pbh[HH + jj];
    const float bG = pbi[2 * HH + jj] + pbh[2 * HH + jj];
    const float bO = pbi[3 * HH + jj] + pbh[3 * HH + jj];
    const int mbase = m0 + wv * 16 + (lane >> 4) * 4;

    for (int n = 0; n <= TLEN; ++n) {
        const int rb = n & 1;
        const bool active = role1 ? (n > 0) : (n < TLEN);
        if (active) {
            const u16 *A1h, *A1l, *A2h, *A2l;
            u16 *wh, *wl;
            if (!role1) {
                A1h = xhi + (size_t)n * DD; A1l = xlo + (size_t)n * DD;
                A2h = rb ? h0hB : h0hA;     A2l = rb ? h0lB : h0lA;
                wh  = rb ? h0hA : h0hB;     wl  = rb ? h0lA : h0lB;   // write parity rb^1
            } else {
                A1h = rb ? h0hB : h0hA;     A1l = rb ? h0lB : h0lA;
                A2h = rb ? h1hB : h1hA;     A2l = rb ? h1lB : h1lA;
                wh  = rb ? h1hA : h1hB;     wl  = rb ? h1lA : h1lB;
            }

            auto bptr = [&](int c, const u16* P1, const u16* P2) -> const u16* {
                return (c < C1) ? (P1 + (size_t)grow * ldb1 + c * 32 + bks)
                                : (P2 + (size_t)grow * HH + (size_t)(c - C1) * 32 + bks);
            };
            auto aptr = [&](int c, const u16* P1, const u16* P2) -> const u16* {
                return (c < C1) ? (P1 + (size_t)arow * ld1 + c * 32 + akq)
                                : (P2 + (size_t)arow * HH + (size_t)(c - C1) * 32 + akq);
            };

            float4v zf = {0.f, 0.f, 0.f, 0.f};
            float4v acc0 = zf, acc1 = zf, acc2 = zf, acc3 = zf;

            // prologue: stage chunk 0, prefetch A frags for chunk 0
            short8 svh = *(const short8*)bptr(0, B1h, B2h);
            short8 svl = *(const short8*)bptr(0, B1l, B2l);
            short8 ah  = *(const short8*)aptr(0, A1h, A2h);
            short8 al  = *(const short8*)aptr(0, A1l, A2l);
            *(short8*)&sBh[0][tid * 8] = svh;
            *(short8*)&sBl[0][tid * 8] = svl;

            for (int c = 0; c < C; ++c) {
                __syncthreads();                   // buf[c&1] staged & visible; prev reads done
                short8 nvh, nvl, nah, nal;
                const bool more = (c + 1 < C);
                if (more) {                        // issue next-chunk loads (overlap with MFMA)
                    nvh = *(const short8*)bptr(c + 1, B1h, B2h);
                    nvl = *(const short8*)bptr(c + 1, B1l, B2l);
                    nah = *(const short8*)aptr(c + 1, A1h, A2h);
                    nal = *(const short8*)aptr(c + 1, A1l, A2l);
                }
                const int buf = c & 1;
                short8 b0h = *(const short8*)&sBh[buf][0 * 512 + fo];
                short8 b1h = *(const short8*)&sBh[buf][1 * 512 + fo];
                short8 b2h = *(const short8*)&sBh[buf][2 * 512 + fo];
                short8 b3h = *(const short8*)&sBh[buf][3 * 512 + fo];
                short8 b0l = *(const short8*)&sBl[buf][0 * 512 + fo];
                short8 b1l = *(const short8*)&sBl[buf][1 * 512 + fo];
                short8 b2l = *(const short8*)&sBl[buf][2 * 512 + fo];
                short8 b3l = *(const short8*)&sBl[buf][3 * 512 + fo];

                acc0 = __builtin_amdgcn_mfma_f32_16x16x32_bf16(ah, b0h, acc0, 0, 0, 0);
                acc1 = __builtin_amdgcn_mfma_f32_16x16x32_bf16(ah, b1h, acc1, 0, 0, 0);
                acc2 = __builtin_amdgcn_mfma_f32_16x16x32_bf16(ah, b2h, acc2, 0, 0, 0);
                acc3 = __builtin_amdgcn_mfma_f32_16x16x32_bf16(ah, b3h, acc3, 0, 0, 0);
                acc0 = __builtin_amdgcn_mfma_f32_16x16x32_bf16(ah, b0l, acc0, 0, 0, 0);
                acc1 = __builtin_amdgcn_mfma_f32_16x16x32_bf16(ah, b1l, acc1, 0, 0, 0);
                acc2 = __builtin_amdgcn_mfma_f32_16x16x32_bf16(ah, b2l, acc2, 0, 0, 0);
                acc3 = __builtin_amdgcn_mfma_f32_16x16x32_bf16(ah, b3l, acc3, 0, 0, 0);
                acc0 = __builtin_amdgcn_mfma_f32_16x16x32_bf16(al, b0h, acc0, 0, 0, 0);
                acc1 = __builtin_amdgcn_mfma_f32_16x16x32_bf16(al, b1h, acc1, 0, 0, 0);
                acc2 = __builtin_amdgcn_mfma_f32_16x16x32_bf16(al, b2h, acc2, 0, 0, 0);
                acc3 = __builtin_amdgcn_mfma_f32_16x16x32_bf16(al, b3h, acc3, 0, 0, 0);

                if (more) {
                    *(short8*)&sBh[buf ^ 1][tid * 8] = nvh;  // waits vmcnt for staged loads
                    *(short8*)&sBl[buf ^ 1][tid * 8] = nvl;
                    ah = nah; al = nal;
                }
            }

            // epilogue: all 4 gates of (m, j) live in this lane
#pragma unroll
            for (int r = 0; r < 4; ++r) {
                const size_t off = (size_t)(mbase + r) * HH + jj;
                float gi = acc0[r] + bI;
                float gf = acc1[r] + bF;
                float gg = acc2[r] + bG;
                float go = acc3[r] + bO;
                float cp = cc[off];
                float cn = sigm(gf) * cp + sigm(gi) * tanhf(gg);
                float h  = sigm(go) * tanhf(cn);
                cc[off] = cn;
                u16 hv = bf16rn(h);
                wh[off] = hv;
                wl[off] = bf16rn(h - bf16tf(hv));
                if (role1) h1last[off] = h;
            }
        }

        // ---- m-group barrier (64 blocks), sense-reversing, device scope ----
        // syncthreads drains this block's writes (vmcnt 0 before s_barrier);
        // thread0's ACQ_REL RMW releases them agent-wide; spinners' / last-arriver's
        // acquire invalidates this CU's L1 + XCD L2 so next-iter reads are fresh.
        __syncthreads();
        if (tid == 0) {
            unsigned g = __hip_atomic_load(bgen, __ATOMIC_RELAXED, __HIP_MEMORY_SCOPE_AGENT);
            unsigned a = __hip_atomic_fetch_add(bcnt, 1u, __ATOMIC_ACQ_REL, __HIP_MEMORY_SCOPE_AGENT);
            if (a == 63u) {
                __hip_atomic_store(bcnt, 0u, __ATOMIC_RELAXED, __HIP_MEMORY_SCOPE_AGENT);
                __hip_atomic_store(bgen, g + 1u, __ATOMIC_RELEASE, __HIP_MEMORY_SCOPE_AGENT);
            } else {
                while (__hip_atomic_load(bgen, __ATOMIC_ACQUIRE, __HIP_MEMORY_SCOPE_AGENT) == g) {
                    __builtin_amdgcn_s_sleep(2);
                }
            }
        }
        __syncthreads();
    }
}

// ---------------- FC head (fp32, proven in round 1) ----------------

template <int MODE>
__global__ __launch_bounds__(256) void gemm_step(
    const float* __restrict__ A1, int lda1, int K1, const float* __restrict__ W1,
    const float* __restrict__ A2, int K2, const float* __restrict__ W2,
    const float* __restrict__ b1, const float* __restrict__ b2,
    const float* __restrict__ c_in, float* __restrict__ c_out,
    float* __restrict__ h_out)
{
    __shared__ float sA[16][33];
    __shared__ float sW[128][33];

    const int tid = threadIdx.x;
    const int tj  = tid & 31;
    const int tg  = tid >> 5;
    const int m0  = blockIdx.x * 16;
    const int j0  = blockIdx.y * ((MODE == 0) ? 32 : 128);

    float acc[2][4] = {{0.f, 0.f, 0.f, 0.f}, {0.f, 0.f, 0.f, 0.f}};

    for (int seg = 0; seg < 2; ++seg) {
        const float* A  = seg ? A2 : A1;
        const float* W  = seg ? W2 : W1;
        const int    K  = seg ? K2 : K1;
        const int    ld = seg ? HH : lda1;
        if (K == 0) continue;
        for (int kb = 0; kb < K; kb += 32) {
            __syncthreads();
            {
                int idxq = tid;
#pragma unroll
                for (int r = 0; r < 2; ++r, idxq += 256) {
                    int row = idxq >> 5, col = idxq & 31;
                    sA[row][col] = A[(m0 + row) * ld + kb + col];
                }
            }
            {
#pragma unroll
                for (int i = 0; i < 16; ++i) {
                    int idxq = i * 256 + tid;
                    int row = idxq >> 5, col = idxq & 31;
                    int grw;
                    if (MODE == 0) grw = (row >> 5) * HH + j0 + (row & 31);
                    else           grw = j0 + row;
                    sW[row][col] = W[grw * K + kb + col];
                }
            }
            __syncthreads();
#pragma unroll
            for (int k = 0; k < 32; ++k) {
                float a0 = sA[tg][k];
                float a1 = sA[tg + 8][k];
                float w0 = sW[tj][k];
                float w1 = sW[32 + tj][k];
                float w2 = sW[64 + tj][k];
                float w3 = sW[96 + tj][k];
                acc[0][0] += a0 * w0; acc[0][1] += a0 * w1;
                acc[0][2] += a0 * w2; acc[0][3] += a0 * w3;
                acc[1][0] += a1 * w0; acc[1][1] += a1 * w1;
                acc[1][2] += a1 * w2; acc[1][3] += a1 * w3;
            }
        }
    }

    if (MODE == 0) {
        const int j = j0 + tj;
        const float bi = b1[j] + b2[j];
        const float bf = b1[HH + j] + b2[HH + j];
        const float bg = b1[2 * HH + j] + b2[2 * HH + j];
        const float bo = b1[3 * HH + j] + b2[3 * HH + j];
#pragma unroll
        for (int r = 0; r < 2; ++r) {
            int m = m0 + tg + r * 8;
            float gi = acc[r][0] + bi;
            float gf = acc[r][1] + bf;
            float gg = acc[r][2] + bg;
            float go = acc[r][3] + bo;
            float cp = c_in[m * HH + j];
            float c  = sigm(gf) * cp + sigm(gi) * tanhf(gg);
            float h  = sigm(go) * tanhf(c);
            c_out[m * HH + j] = c;
            h_out[m * HH + j] = h;
        }
    } else {
#pragma unroll
        for (int r = 0; r < 2; ++r) {
            int m = m0 + tg + r * 8;
#pragma unroll
            for (int q = 0; q < 4; ++q) {
                int nn = j0 + q * 32 + tj;
                float v = acc[r][q] + b1[nn];
                h_out[m * HH + nn] = fmaxf(v, 0.f);
            }
        }
    }
}

__global__ __launch_bounds__(64) void fc2_kernel(
    const float* __restrict__ z, const float* __restrict__ W,
    const float* __restrict__ b, float* __restrict__ out)
{
    int m = blockIdx.x;
    int lane = threadIdx.x;
    float zr[8];
#pragma unroll
    for (int u = 0; u < 8; ++u) zr[u] = z[m * 512 + u * 64 + lane];
#pragma unroll
    for (int o = 0; o < 8; ++o) {
        float s = 0.f;
#pragma unroll
        for (int u = 0; u < 8; ++u) s += zr[u] * W[o * 512 + u * 64 + lane];
#pragma unroll
        for (int off = 32; off > 0; off >>= 1) s += __shfl_down(s, off);
        if (lane == 0) out[m * 8 + o] = s + b[o];
    }
}

__global__ __launch_bounds__(256) void zero_f_kernel(float* p, int n)
{
    int i = blockIdx.x * 256 + threadIdx.x;
    if (i < n) p[i] = 0.f;
}

// ---------------- host ----------------

extern "C" void kernel_launch(void* const* d_in, const int* in_sizes, int n_in,
                              void* d_out, int out_size, void* d_ws, size_t ws_size,
                              hipStream_t stream)
{
    const float* x     = (const float*)d_in[0];
    const float* W_ih0 = (const float*)d_in[1];
    const float* W_hh0 = (const float*)d_in[2];
    const float* b_ih0 = (const float*)d_in[3];
    const float* b_hh0 = (const float*)d_in[4];
    const float* W_ih1 = (const float*)d_in[5];
    const float* W_hh1 = (const float*)d_in[6];
    const float* b_ih1 = (const float*)d_in[7];
    const float* b_hh1 = (const float*)d_in[8];
    const float* W_fc1 = (const float*)d_in[9];
    const float* b_fc1 = (const float*)d_in[10];
    const float* W_fc2 = (const float*)d_in[11];
    const float* b_fc2 = (const float*)d_in[12];
    float* out = (float*)d_out;

    const size_t S  = (size_t)BB * HH;        // 131072 elems
    const size_t SB = S * sizeof(u16);        // 262144 B
    const size_t SF = S * sizeof(float);      // 524288 B

    const size_t NEED = 2097152 + 1024 /*zero region incl. barriers*/ +
                        4 * SB /*other h bufs*/ +
                        2 * SF /*h1last,zfc*/ + 2 * (size_t)BB * TLEN * DD * 2 /*x split*/ +
                        2 * 131072 * 2 /*Wih0*/ + 3 * 2 * 1048576 * 2 /*Whh0,Wih1,Whh1*/;

    if (ws_size >= NEED) {
        char* W = (char*)d_ws;
        size_t o = 0;
        u16 *h0hi[2], *h0lo[2], *h1hi[2], *h1lo[2];
        // zero region first (2 MB + 1 KB): initial-parity h bufs, c0/c1, barriers
        h0hi[0] = (u16*)(W + o); o += SB;
        h0lo[0] = (u16*)(W + o); o += SB;
        h1hi[1] = (u16*)(W + o); o += SB;
        h1lo[1] = (u16*)(W + o); o += SB;
        float* c0 = (float*)(W + o); o += SF;
        float* c1 = (float*)(W + o); o += SF;
        unsigned* bar = (unsigned*)(W + o); o += 1024;   // 4 groups x (cnt,gen)
        // rest
        h0hi[1] = (u16*)(W + o); o += SB;
        h0lo[1] = (u16*)(W + o); o += SB;
        h1hi[0] = (u16*)(W + o); o += SB;
        h1lo[0] = (u16*)(W + o); o += SB;
        float* h1last = (float*)(W + o); o += SF;
        float* zfc    = (float*)(W + o); o += SF;
        const size_t XN = (size_t)BB * TLEN * DD; // 8388608
        u16* xhi = (u16*)(W + o); o += XN * 2;
        u16* xlo = (u16*)(W + o); o += XN * 2;
        u16* wih0h = (u16*)(W + o); o += 131072 * 2;
        u16* wih0l = (u16*)(W + o); o += 131072 * 2;
        u16* whh0h = (u16*)(W + o); o += 1048576 * 2;
        u16* whh0l = (u16*)(W + o); o += 1048576 * 2;
        u16* wih1h = (u16*)(W + o); o += 1048576 * 2;
        u16* wih1l = (u16*)(W + o); o += 1048576 * 2;
        u16* whh1h = (u16*)(W + o); o += 1048576 * 2;
        u16* whh1l = (u16*)(W + o); o += 1048576 * 2;

        // zero-init: 2 MB + 1 KB = 524544 u32
        zero_kernel<<<2049, 256, 0, stream>>>((unsigned*)d_ws, 524544);
        // splits
        split_kernel<<<2048, 256, 0, stream>>>(x, xhi, xlo, (int)XN);
        split_kernel<<<512, 256, 0, stream>>>(W_ih0, wih0h, wih0l, 131072);
        split_kernel<<<2048, 256, 0, stream>>>(W_hh0, whh0h, whh0l, 1048576);
        split_kernel<<<2048, 256, 0, stream>>>(W_ih1, wih1h, wih1l, 1048576);
        split_kernel<<<2048, 256, 0, stream>>>(W_hh1, whh1h, whh1l, 1048576);

        // one persistent launch replaces 513 serialized dispatches
        lstm_persistent<<<256, 256, 0, stream>>>(
            xhi, xlo,
            wih0h, wih0l, whh0h, whh0l,
            wih1h, wih1l, whh1h, whh1l,
            b_ih0, b_hh0, b_ih1, b_hh1,
            h0hi[0], h0lo[0], h0hi[1], h0lo[1],
            h1hi[0], h1lo[0], h1hi[1], h1lo[1],
            c0, c1, h1last, bar);

        dim3 grid_fc1(BB / 16, 512 / 128);
        gemm_step<1><<<grid_fc1, 256, 0, stream>>>(
            h1last, HH, HH, W_fc1, nullptr, 0, nullptr,
            b_fc1, nullptr, nullptr, nullptr, zfc);
        fc2_kernel<<<BB, 64, 0, stream>>>(zfc, W_fc2, b_fc2, out);
        return;
    }

    // -------- fallback: round-1 fp32 path (needs ~3.7 MB ws) --------
    float* wsf = (float*)d_ws;
    float* h0a = wsf + 0 * S;
    float* c0  = wsf + 1 * S;
    float* h1a = wsf + 2 * S;
    float* c1  = wsf + 3 * S;
    float* h0b = wsf + 4 * S;
    float* h1b = wsf + 5 * S;
    float* zb  = wsf + 6 * S;
    float* h0buf[2] = {h0a, h0b};
    float* h1buf[2] = {h1a, h1b};

    zero_f_kernel<<<(int)((4 * S + 255) / 256), 256, 0, stream>>>(wsf, (int)(4 * S));

    dim3 grid_lstm(BB / 16, HH / 32);
    for (int t = 0; t < TLEN; ++t) {
        const float* xt = x + (size_t)t * DD;
        gemm_step<0><<<grid_lstm, 256, 0, stream>>>(
            xt, TLEN * DD, DD, W_ih0,
            h0buf[t & 1], HH, W_hh0,
            b_ih0, b_hh0, c0, c0, h0buf[(t + 1) & 1]);
        gemm_step<0><<<grid_lstm, 256, 0, stream>>>(
            h0buf[(t + 1) & 1], HH, HH, W_ih1,
            h1buf[t & 1], HH, W_hh1,
            b_ih1, b_hh1, c1, c1, h1buf[(t + 1) & 1]);
    }
    dim3 grid_fc1(BB / 16, 512 / 128);
    gemm_step<1><<<grid_fc1, 256, 0, stream>>>(
        h1buf[0], HH, HH, W_fc1, nullptr, 0, nullptr,
        b_fc1, nullptr, nullptr, nullptr, zb);
    fc2_kernel<<<BB, 64, 0, stream>>>(zb, W_fc2, b_fc2, out);
}

// Round 2
// 8087.931 us; speedup vs baseline: 3.6122x; 3.6122x over previous
//
#include <hip/hip_runtime.h>
#include <math.h>

typedef unsigned short u16;
typedef __attribute__((ext_vector_type(8))) short short8;
typedef __attribute__((ext_vector_type(4))) float float4v;

#define HH   512
#define BB   256
#define TLEN 512
#define DD   64

__device__ __forceinline__ float sigm(float x) { return 1.0f / (1.0f + __expf(-x)); }

__device__ __forceinline__ u16 bf16rn(float v) {
    unsigned u = __float_as_uint(v);
    u += 0x7fffu + ((u >> 16) & 1u);
    return (u16)(u >> 16);
}
__device__ __forceinline__ float bf16tf(u16 h) { return __uint_as_float(((unsigned)h) << 16); }

// ---------------- precompute kernels ----------------

__global__ __launch_bounds__(256) void split_kernel(const float* __restrict__ src,
                                                    u16* __restrict__ hi, u16* __restrict__ lo, int n)
{
    for (int i = blockIdx.x * 256 + threadIdx.x; i < n; i += gridDim.x * 256) {
        float v = src[i];
        u16 h = bf16rn(v);
        hi[i] = h;
        lo[i] = bf16rn(v - bf16tf(h));
    }
}

__global__ __launch_bounds__(256) void zero_kernel(unsigned* p, int n)
{
    int i = blockIdx.x * 256 + threadIdx.x;
    if (i < n) p[i] = 0u;
}

// ---------------- persistent fused LSTM, weights register-resident ----------------
// 256 blocks x 512 threads (8 waves), 1 block/CU (VGPR-bound), all co-resident.
// Block roles as before: blockIdx<128 -> layer0 step t=n; >=128 -> layer1 step t=n-1.
// Wave w: gate g=w&3, k-half kh=w>>2. B slice (gate g, 16 j-cols, k-half) lives in
// 128 VGPRs (hi+lo), loaded ONCE -> immune to the per-step L2 invalidation that made
// round-1 refetch 31 MB/step. A (h-state) staged per 32-k chunk into LDS
// (stride-80B rows: 2-way bank aliasing = free, vs old 8-way). Gate partials are
// exchanged once per step through LDS; c-state lives in registers.
// Barrier: relaxed spin (coherent, NO invalidate) + one acquire per block per step.

template<int NKT, int C1, bool ROLE1>
__device__ void lstm_body(
    const u16* __restrict__ X1h, const u16* __restrict__ X1l,
    const u16* __restrict__ B1h, const u16* __restrict__ B1l, const int ldb1,
    const u16* __restrict__ B2h, const u16* __restrict__ B2l,
    const float* __restrict__ pbi, const float* __restrict__ pbh,
    u16* h0hA, u16* h0lA, u16* h0hB, u16* h0lB,
    u16* h1hA, u16* h1lA, u16* h1hB, u16* h1lB,
    float* __restrict__ h1last,
    unsigned* bcnt, unsigned* bgen,
    const int m0, const int j0, u16* smem)
{
    const int tid  = threadIdx.x;
    const int lane = tid & 63;
    const int wv   = tid >> 6;
    const int g    = wv & 3;
    const int kh   = wv >> 2;
    float* sX = (float*)smem;   // [8][64][18] f32 exchange, aliases A staging (sync'd)

    // ---- load this wave's B slice into registers, once ----
    short8 rBh[NKT], rBl[NKT];
    {
        const size_t brow = (size_t)(g * HH + j0 + (lane & 15));
        const int kq = (lane >> 4) * 8;
#pragma unroll
        for (int i = 0; i < NKT; ++i) {
            const int kt = kh * NKT + i;
            const u16 *ph, *pl;
            if (kt < C1) {
                ph = B1h + brow * (size_t)ldb1 + kt * 32 + kq;
                pl = B1l + brow * (size_t)ldb1 + kt * 32 + kq;
            } else {
                ph = B2h + brow * HH + (size_t)(kt - C1) * 32 + kq;
                pl = B2l + brow * HH + (size_t)(kt - C1) * 32 + kq;
            }
            rBh[i] = *(const short8*)ph;
            rBl[i] = *(const short8*)pl;
        }
    }

    // ---- staging constants: 2 x 16B per thread per chunk (16 KB total) ----
    // tiles: (half kh', hi/lo) -> 64 rows x 32 k, LDS row stride 40 u16 (80 B)
    int half_[2], hl_[2], r_[2], ks_[2], loff_[2];
#pragma unroll
    for (int q = 0; q < 2; ++q) {
        const int idx = q * 512 + tid;
        const int tile = idx >> 8;          // 0..3: half = tile>>1, hl = tile&1
        half_[q] = tile >> 1;
        hl_[q]   = tile & 1;
        const int t8 = idx & 255;
        r_[q]  = t8 >> 2;
        ks_[q] = (t8 & 3) * 8;
        loff_[q] = (half_[q] * 2 + hl_[q]) * 2560 + r_[q] * 40 + ks_[q];
    }

    // ---- epilogue constants: thread t -> (j = t&15, m-pair = t>>4) ----
    const int jj  = j0 + (tid & 15);
    const int mb2 = (tid >> 4) * 2;
    const float bI = pbi[jj] + pbh[jj];
    const float bF = pbi[HH + jj] + pbh[HH + jj];
    const float bG = pbi[2 * HH + jj] + pbh[2 * HH + jj];
    const float bO = pbi[3 * HH + jj] + pbh[3 * HH + jj];
    float cst0 = 0.f, cst1 = 0.f;   // c-state in registers, never in memory

    const int ab0 = kh * 2 * 2560 + (lane & 15) * 40 + (lane >> 4) * 8;

    for (int n = 0; n <= TLEN; ++n) {
        const int rb = n & 1;
        const bool active = ROLE1 ? (n > 0) : (n < TLEN);
        if (active) {
            const u16 *A1h_, *A1l_, *A2h_, *A2l_;
            u16 *wh, *wl;
            size_t ld1;
            if (ROLE1) {
                A1h_ = rb ? h0hB : h0hA; A1l_ = rb ? h0lB : h0lA;
                A2h_ = rb ? h1hB : h1hA; A2l_ = rb ? h1lB : h1lA;
                wh   = rb ? h1hA : h1hB; wl   = rb ? h1lA : h1lB;
                ld1 = HH;
            } else {
                A1h_ = X1h + (size_t)n * DD; A1l_ = X1l + (size_t)n * DD;
                A2h_ = rb ? h0hB : h0hA;     A2l_ = rb ? h0lB : h0lA;
                wh   = rb ? h0hA : h0hB;     wl   = rb ? h0lA : h0lB;
                ld1 = (size_t)TLEN * DD;
            }

            auto srcp = [&](int kt, int r, int ks, int lo) -> const u16* {
                if (kt < C1) return (lo ? A1l_ : A1h_) + (size_t)(m0 + r) * ld1 + kt * 32 + ks;
                return (lo ? A2l_ : A2h_) + (size_t)(m0 + r) * HH + (size_t)(kt - C1) * 32 + ks;
            };

            float4v acc[4];
#pragma unroll
            for (int mt = 0; mt < 4; ++mt) acc[mt] = (float4v){0.f, 0.f, 0.f, 0.f};

            // prologue: stage chunk 0
            {
                short8 v0 = *(const short8*)srcp(half_[0] * NKT, r_[0], ks_[0], hl_[0]);
                short8 v1 = *(const short8*)srcp(half_[1] * NKT, r_[1], ks_[1], hl_[1]);
                *(short8*)&smem[loff_[0]] = v0;
                *(short8*)&smem[loff_[1]] = v1;
            }

#pragma unroll
            for (int i = 0; i < NKT; ++i) {
                __syncthreads();               // buf[i&1] staged; prev reads done
                short8 nv0, nv1;
                const bool more = (i + 1 < NKT);
                if (more) {                    // overlap next-chunk loads with MFMA
                    nv0 = *(const short8*)srcp(half_[0] * NKT + i + 1, r_[0], ks_[0], hl_[0]);
                    nv1 = *(const short8*)srcp(half_[1] * NKT + i + 1, r_[1], ks_[1], hl_[1]);
                }
                const int buf = i & 1;
                const int ab = buf * 10240 + ab0;
                short8 aH[4], aL[4];
#pragma unroll
                for (int mt = 0; mt < 4; ++mt) {
                    aH[mt] = *(const short8*)&smem[ab + mt * 640];
                    aL[mt] = *(const short8*)&smem[ab + 2560 + mt * 640];
                }
#pragma unroll
                for (int mt = 0; mt < 4; ++mt) {
                    acc[mt] = __builtin_amdgcn_mfma_f32_16x16x32_bf16(aH[mt], rBh[i], acc[mt], 0, 0, 0);
                    acc[mt] = __builtin_amdgcn_mfma_f32_16x16x32_bf16(aH[mt], rBl[i], acc[mt], 0, 0, 0);
                    acc[mt] = __builtin_amdgcn_mfma_f32_16x16x32_bf16(aL[mt], rBh[i], acc[mt], 0, 0, 0);
                }
                if (more) {
                    *(short8*)&smem[(buf ^ 1) * 10240 + loff_[0]] = nv0;
                    *(short8*)&smem[(buf ^ 1) * 10240 + loff_[1]] = nv1;
                }
            }

            // ---- gate/k-half exchange via LDS (aliases staging buffers; sync'd) ----
            __syncthreads();
#pragma unroll
            for (int mt = 0; mt < 4; ++mt)
#pragma unroll
                for (int r = 0; r < 4; ++r)
                    sX[wv * 1152 + (mt * 16 + (lane >> 4) * 4 + r) * 18 + (lane & 15)] = acc[mt][r];
            __syncthreads();

#pragma unroll
            for (int p = 0; p < 2; ++p) {
                const int m = mb2 + p;
                const int xb = m * 18 + (tid & 15);
                const float gi = sX[0 * 1152 + xb] + sX[4 * 1152 + xb] + bI;
                const float gf = sX[1 * 1152 + xb] + sX[5 * 1152 + xb] + bF;
                const float gg = sX[2 * 1152 + xb] + sX[6 * 1152 + xb] + bG;
                const float go = sX[3 * 1152 + xb] + sX[7 * 1152 + xb] + bO;
                const float cp = p ? cst1 : cst0;
                const float cn = sigm(gf) * cp + sigm(gi) * tanhf(gg);
                const float h  = sigm(go) * tanhf(cn);
                if (p) cst1 = cn; else cst0 = cn;
                const size_t off = (size_t)(m0 + m) * HH + jj;
                const u16 hv = bf16rn(h);
                wh[off] = hv;
                wl[off] = bf16rn(h - bf16tf(hv));
                if (ROLE1 && n == TLEN) h1last[off] = h;
            }
        }

        // ---- m-group barrier: relaxed spin, ONE acquire per block per step ----
        __syncthreads();   // drains vmcnt(0): h stores are in L2 before release
        if (tid == 0) {
            const unsigned g0 = __hip_atomic_load(bgen, __ATOMIC_RELAXED, __HIP_MEMORY_SCOPE_AGENT);
            const unsigned a = __hip_atomic_fetch_add(bcnt, 1u, __ATOMIC_RELEASE, __HIP_MEMORY_SCOPE_AGENT);
            if (a == 63u) {
                __hip_atomic_store(bcnt, 0u, __ATOMIC_RELAXED, __HIP_MEMORY_SCOPE_AGENT);
                __hip_atomic_store(bgen, g0 + 1u, __ATOMIC_RELEASE, __HIP_MEMORY_SCOPE_AGENT);
            } else {
                int sp = 0;
                while (__hip_atomic_load(bgen, __ATOMIC_RELAXED, __HIP_MEMORY_SCOPE_AGENT) == g0) {
                    __builtin_amdgcn_s_sleep(2);
                    if ((++sp & 63) == 0)   // safety net: periodic coherent-forcing poll
                        (void)__hip_atomic_load(bgen, __ATOMIC_ACQUIRE, __HIP_MEMORY_SCOPE_AGENT);
                }
            }
            // single acquire: invalidate L1/L2 once so next step's h reads are fresh.
            // Weights are in registers -> invalidation no longer costs refetch.
            (void)__hip_atomic_load(bgen, __ATOMIC_ACQUIRE, __HIP_MEMORY_SCOPE_AGENT);
        }
        __syncthreads();
    }
}

__global__ __launch_bounds__(512) void lstm_persistent(
    const u16* __restrict__ xhi, const u16* __restrict__ xlo,
    const u16* __restrict__ Wih0h, const u16* __restrict__ Wih0l,
    const u16* __restrict__ Whh0h, const u16* __restrict__ Whh0l,
    const u16* __restrict__ Wih1h, const u16* __restrict__ Wih1l,
    const u16* __restrict__ Whh1h, const u16* __restrict__ Whh1l,
    const float* __restrict__ bi0, const float* __restrict__ bh0,
    const float* __restrict__ bi1, const float* __restrict__ bh1,
    u16* h0hA, u16* h0lA, u16* h0hB, u16* h0lB,
    u16* h1hA, u16* h1lA, u16* h1hB, u16* h1lB,
    float* __restrict__ h1last, unsigned* bar)
{
    __shared__ u16 smem[20480];   // 40 KB: 2buf x 2half x 2(hi/lo) x (64 x 40) u16
    const bool role1 = (blockIdx.x >= 128);
    const int idx = blockIdx.x & 127;
    const int m0 = (idx & 3) * 64;
    const int j0 = (idx >> 2) * 16;
    const int gid = idx & 3;
    unsigned* bcnt = bar + gid * 64;
    unsigned* bgen = bar + gid * 64 + 32;

    if (role1)
        lstm_body<16, 16, true>(nullptr, nullptr,
            Wih1h, Wih1l, HH, Whh1h, Whh1l, bi1, bh1,
            h0hA, h0lA, h0hB, h0lB, h1hA, h1lA, h1hB, h1lB,
            h1last, bcnt, bgen, m0, j0, smem);
    else
        lstm_body<9, 2, false>(xhi, xlo,
            Wih0h, Wih0l, DD, Whh0h, Whh0l, bi0, bh0,
            h0hA, h0lA, h0hB, h0lB, h1hA, h1lA, h1hB, h1lB,
            nullptr, bcnt, bgen, m0, j0, smem);
}

// ---------------- FC head (fp32, proven) ----------------

template <int MODE>
__global__ __launch_bounds__(256) void gemm_step(
    const float* __restrict__ A1, int lda1, int K1, const float* __restrict__ W1,
    const float* __restrict__ A2, int K2, const float* __restrict__ W2,
    const float* __restrict__ b1, const float* __restrict__ b2,
    const float* __restrict__ c_in, float* __restrict__ c_out,
    float* __restrict__ h_out)
{
    __shared__ float sA[16][33];
    __shared__ float sW[128][33];

    const int tid = threadIdx.x;
    const int tj  = tid & 31;
    const int tg  = tid >> 5;
    const int m0  = blockIdx.x * 16;
    const int j0  = blockIdx.y * ((MODE == 0) ? 32 : 128);

    float acc[2][4] = {{0.f, 0.f, 0.f, 0.f}, {0.f, 0.f, 0.f, 0.f}};

    for (int seg = 0; seg < 2; ++seg) {
        const float* A  = seg ? A2 : A1;
        const float* W  = seg ? W2 : W1;
        const int    K  = seg ? K2 : K1;
        const int    ld = seg ? HH : lda1;
        if (K == 0) continue;
        for (int kb = 0; kb < K; kb += 32) {
            __syncthreads();
            {
                int idxq = tid;
#pragma unroll
                for (int r = 0; r < 2; ++r, idxq += 256) {
                    int row = idxq >> 5, col = idxq & 31;
                    sA[row][col] = A[(m0 + row) * ld + kb + col];
                }
            }
            {
#pragma unroll
                for (int i = 0; i < 16; ++i) {
                    int idxq = i * 256 + tid;
                    int row = idxq >> 5, col = idxq & 31;
                    int grw;
                    if (MODE == 0) grw = (row >> 5) * HH + j0 + (row & 31);
                    else           grw = j0 + row;
                    sW[row][col] = W[grw * K + kb + col];
                }
            }
            __syncthreads();
#pragma unroll
            for (int k = 0; k < 32; ++k) {
                float a0 = sA[tg][k];
                float a1 = sA[tg + 8][k];
                float w0 = sW[tj][k];
                float w1 = sW[32 + tj][k];
                float w2 = sW[64 + tj][k];
                float w3 = sW[96 + tj][k];
                acc[0][0] += a0 * w0; acc[0][1] += a0 * w1;
                acc[0][2] += a0 * w2; acc[0][3] += a0 * w3;
                acc[1][0] += a1 * w0; acc[1][1] += a1 * w1;
                acc[1][2] += a1 * w2; acc[1][3] += a1 * w3;
            }
        }
    }

    if (MODE == 0) {
        const int j = j0 + tj;
        const float bi = b1[j] + b2[j];
        const float bf = b1[HH + j] + b2[HH + j];
        const float bg = b1[2 * HH + j] + b2[2 * HH + j];
        const float bo = b1[3 * HH + j] + b2[3 * HH + j];
#pragma unroll
        for (int r = 0; r < 2; ++r) {
            int m = m0 + tg + r * 8;
            float gi = acc[r][0] + bi;
            float gf = acc[r][1] + bf;
            float gg = acc[r][2] + bg;
            float go = acc[r][3] + bo;
            float cp = c_in[m * HH + j];
            float c  = sigm(gf) * cp + sigm(gi) * tanhf(gg);
            float h  = sigm(go) * tanhf(c);
            c_out[m * HH + j] = c;
            h_out[m * HH + j] = h;
        }
    } else {
#pragma unroll
        for (int r = 0; r < 2; ++r) {
            int m = m0 + tg + r * 8;
#pragma unroll
            for (int q = 0; q < 4; ++q) {
                int nn = j0 + q * 32 + tj;
                float v = acc[r][q] + b1[nn];
                h_out[m * HH + nn] = fmaxf(v, 0.f);
            }
        }
    }
}

__global__ __launch_bounds__(64) void fc2_kernel(
    const float* __restrict__ z, const float* __restrict__ W,
    const float* __restrict__ b, float* __restrict__ out)
{
    int m = blockIdx.x;
    int lane = threadIdx.x;
    float zr[8];
#pragma unroll
    for (int u = 0; u < 8; ++u) zr[u] = z[m * 512 + u * 64 + lane];
#pragma unroll
    for (int o = 0; o < 8; ++o) {
        float s = 0.f;
#pragma unroll
        for (int u = 0; u < 8; ++u) s += zr[u] * W[o * 512 + u * 64 + lane];
#pragma unroll
        for (int off = 32; off > 0; off >>= 1) s += __shfl_down(s, off);
        if (lane == 0) out[m * 8 + o] = s + b[o];
    }
}

__global__ __launch_bounds__(256) void zero_f_kernel(float* p, int n)
{
    int i = blockIdx.x * 256 + threadIdx.x;
    if (i < n) p[i] = 0.f;
}

// ---------------- host ----------------

extern "C" void kernel_launch(void* const* d_in, const int* in_sizes, int n_in,
                              void* d_out, int out_size, void* d_ws, size_t ws_size,
                              hipStream_t stream)
{
    const float* x     = (const float*)d_in[0];
    const float* W_ih0 = (const float*)d_in[1];
    const float* W_hh0 = (const float*)d_in[2];
    const float* b_ih0 = (const float*)d_in[3];
    const float* b_hh0 = (const float*)d_in[4];
    const float* W_ih1 = (const float*)d_in[5];
    const float* W_hh1 = (const float*)d_in[6];
    const float* b_ih1 = (const float*)d_in[7];
    const float* b_hh1 = (const float*)d_in[8];
    const float* W_fc1 = (const float*)d_in[9];
    const float* b_fc1 = (const float*)d_in[10];
    const float* W_fc2 = (const float*)d_in[11];
    const float* b_fc2 = (const float*)d_in[12];
    float* out = (float*)d_out;

    const size_t S  = (size_t)BB * HH;        // 131072 elems
    const size_t SB = S * sizeof(u16);        // 262144 B
    const size_t SF = S * sizeof(float);      // 524288 B

    const size_t NEED = 2097152 + 1024 /*zero region incl. barriers*/ +
                        4 * SB /*other h bufs*/ +
                        2 * SF /*h1last,zfc*/ + 2 * (size_t)BB * TLEN * DD * 2 /*x split*/ +
                        2 * 131072 * 2 /*Wih0*/ + 3 * 2 * 1048576 * 2 /*Whh0,Wih1,Whh1*/;

    if (ws_size >= NEED) {
        char* W = (char*)d_ws;
        size_t o = 0;
        u16 *h0hi[2], *h0lo[2], *h1hi[2], *h1lo[2];
        // zero region first (2 MB + 1 KB): initial-parity h bufs, c0/c1, barriers
        h0hi[0] = (u16*)(W + o); o += SB;
        h0lo[0] = (u16*)(W + o); o += SB;
        h1hi[1] = (u16*)(W + o); o += SB;
        h1lo[1] = (u16*)(W + o); o += SB;
        float* c0 = (float*)(W + o); o += SF;   // unused by persistent path (kept for layout)
        float* c1 = (float*)(W + o); o += SF;
        unsigned* bar = (unsigned*)(W + o); o += 1024;   // 4 groups x (cnt,gen)
        (void)c0; (void)c1;
        // rest
        h0hi[1] = (u16*)(W + o); o += SB;
        h0lo[1] = (u16*)(W + o); o += SB;
        h1hi[0] = (u16*)(W + o); o += SB;
        h1lo[0] = (u16*)(W + o); o += SB;
        float* h1last = (float*)(W + o); o += SF;
        float* zfc    = (float*)(W + o); o += SF;
        const size_t XN = (size_t)BB * TLEN * DD; // 8388608
        u16* xhi = (u16*)(W + o); o += XN * 2;
        u16* xlo = (u16*)(W + o); o += XN * 2;
        u16* wih0h = (u16*)(W + o); o += 131072 * 2;
        u16* wih0l = (u16*)(W + o); o += 131072 * 2;
        u16* whh0h = (u16*)(W + o); o += 1048576 * 2;
        u16* whh0l = (u16*)(W + o); o += 1048576 * 2;
        u16* wih1h = (u16*)(W + o); o += 1048576 * 2;
        u16* wih1l = (u16*)(W + o); o += 1048576 * 2;
        u16* whh1h = (u16*)(W + o); o += 1048576 * 2;
        u16* whh1l = (u16*)(W + o); o += 1048576 * 2;

        // zero-init: 2 MB + 1 KB = 524544 u32
        zero_kernel<<<2049, 256, 0, stream>>>((unsigned*)d_ws, 524544);
        // splits
        split_kernel<<<2048, 256, 0, stream>>>(x, xhi, xlo, (int)XN);
        split_kernel<<<512, 256, 0, stream>>>(W_ih0, wih0h, wih0l, 131072);
        split_kernel<<<2048, 256, 0, stream>>>(W_hh0, whh0h, whh0l, 1048576);
        split_kernel<<<2048, 256, 0, stream>>>(W_ih1, wih1h, wih1l, 1048576);
        split_kernel<<<2048, 256, 0, stream>>>(W_hh1, whh1h, whh1l, 1048576);

        lstm_persistent<<<256, 512, 0, stream>>>(
            xhi, xlo,
            wih0h, wih0l, whh0h, whh0l,
            wih1h, wih1l, whh1h, whh1l,
            b_ih0, b_hh0, b_ih1, b_hh1,
            h0hi[0], h0lo[0], h0hi[1], h0lo[1],
            h1hi[0], h1lo[0], h1hi[1], h1lo[1],
            h1last, bar);

        dim3 grid_fc1(BB / 16, 512 / 128);
        gemm_step<1><<<grid_fc1, 256, 0, stream>>>(
            h1last, HH, HH, W_fc1, nullptr, 0, nullptr,
            b_fc1, nullptr, nullptr, nullptr, zfc);
        fc2_kernel<<<BB, 64, 0, stream>>>(zfc, W_fc2, b_fc2, out);
        return;
    }

    // -------- fallback: fp32 path (needs ~3.7 MB ws) --------
    float* wsf = (float*)d_ws;
    float* h0a = wsf + 0 * S;
    float* c0  = wsf + 1 * S;
    float* h1a = wsf + 2 * S;
    float* c1  = wsf + 3 * S;
    float* h0b = wsf + 4 * S;
    float* h1b = wsf + 5 * S;
    float* zb  = wsf + 6 * S;
    float* h0buf[2] = {h0a, h0b};
    float* h1buf[2] = {h1a, h1b};

    zero_f_kernel<<<(int)((4 * S + 255) / 256), 256, 0, stream>>>(wsf, (int)(4 * S));

    dim3 grid_lstm(BB / 16, HH / 32);
    for (int t = 0; t < TLEN; ++t) {
        const float* xt = x + (size_t)t * DD;
        gemm_step<0><<<grid_lstm, 256, 0, stream>>>(
            xt, TLEN * DD, DD, W_ih0,
            h0buf[t & 1], HH, W_hh0,
            b_ih0, b_hh0, c0, c0, h0buf[(t + 1) & 1]);
        gemm_step<0><<<grid_lstm, 256, 0, stream>>>(
            h0buf[(t + 1) & 1], HH, HH, W_ih1,
            h1buf[t & 1], HH, W_hh1,
            b_ih1, b_hh1, c1, c1, h1buf[(t + 1) & 1]);
    }
    dim3 grid_fc1(BB / 16, 512 / 128);
    gemm_step<1><<<grid_fc1, 256, 0, stream>>>(
        h1buf[0], HH, HH, W_fc1, nullptr, 0, nullptr,
        b_fc1, nullptr, nullptr, nullptr, zb);
    fc2_kernel<<<BB, 64, 0, stream>>>(zb, W_fc2, b_fc2, out);
}

// Round 4
// 7321.760 us; speedup vs baseline: 3.9902x; 1.1046x over previous
//
#include <hip/hip_runtime.h>
#include <math.h>

typedef unsigned short u16;
typedef __attribute__((ext_vector_type(8))) short short8;
typedef __attribute__((ext_vector_type(4))) float float4v;

#define HH   512
#define BB   256
#define TLEN 512
#define DD   64

__device__ __forceinline__ float sigm(float x) { return 1.0f / (1.0f + __expf(-x)); }

__device__ __forceinline__ u16 bf16rn(float v) {
    unsigned u = __float_as_uint(v);
    u += 0x7fffu + ((u >> 16) & 1u);
    return (u16)(u >> 16);
}
__device__ __forceinline__ float bf16tf(u16 h) { return __uint_as_float(((unsigned)h) << 16); }

// ---------------- precompute kernels ----------------

__global__ __launch_bounds__(256) void split_kernel(const float* __restrict__ src,
                                                    u16* __restrict__ hi, u16* __restrict__ lo, int n)
{
    for (int i = blockIdx.x * 256 + threadIdx.x; i < n; i += gridDim.x * 256) {
        float v = src[i];
        u16 h = bf16rn(v);
        hi[i] = h;
        lo[i] = bf16rn(v - bf16tf(h));
    }
}

__global__ __launch_bounds__(256) void zero_kernel(unsigned* p, int n)
{
    int i = blockIdx.x * 256 + threadIdx.x;
    if (i < n) p[i] = 0u;
}

// ---------------- persistent fused LSTM ----------------
// Sync protocol: EXACTLY round-2's (proven to run: 8.09 ms, passed) —
// per-m-group gen-based sense-reversing barrier, 64 arrivals (both roles),
// relaxed spin + periodic/final acquire.
// Perf changes vs round 2 (all local to the compute path):
//  1) __launch_bounds__(512,2): 256-VGPR budget so the B-slice (128 VGPR)
//     is truly register-resident (round-2 compiled at 124 VGPR = B was
//     re-loaded from L2 every chunk).
//  2) A-tile LDS staging: 64B rows with 16B-slot XOR swizzle
//     (slot ^= (row>>1)&3) -> <=2-way bank aliasing (free) on both
//     ds_write_b128 staging and ds_read_b128 A-frag reads
//     (round-2: SQ_LDS_BANK_CONFLICT = 6.96e8 from stride-80B layout).
//  3) Depth-2 global->reg->LDS prefetch (chunk i+2 issued during chunk i).

template<int NKT, int C1, bool ROLE1>
__device__ void lstm_body(
    const u16* __restrict__ X1h, const u16* __restrict__ X1l,
    const u16* __restrict__ B1h, const u16* __restrict__ B1l, const int ldb1,
    const u16* __restrict__ B2h, const u16* __restrict__ B2l,
    const float* __restrict__ pbi, const float* __restrict__ pbh,
    u16* __restrict__ h0hA, u16* __restrict__ h0lA,
    u16* __restrict__ h0hB, u16* __restrict__ h0lB,
    u16* __restrict__ h1hA, u16* __restrict__ h1lA,
    u16* __restrict__ h1hB, u16* __restrict__ h1lB,
    float* __restrict__ h1last,
    unsigned* bcnt, unsigned* bgen,
    const int m0, const int j0, u16* smem)
{
    const int tid  = threadIdx.x;
    const int lane = tid & 63;
    const int wv   = tid >> 6;
    const int g    = wv & 3;
    const int kh   = wv >> 2;
    float* sX = (float*)smem;   // [8][64][18] f32 exchange, aliases staging (sync'd)

    // ---- B slice -> registers, once (kh half of K, gate g, 16 j-cols) ----
    short8 rBh[NKT], rBl[NKT];
    {
        const size_t brow = (size_t)(g * HH + j0 + (lane & 15));
        const int kq = (lane >> 4) * 8;
#pragma unroll
        for (int i = 0; i < NKT; ++i) {
            const int kt = kh * NKT + i;
            const u16 *ph, *pl;
            if (kt < C1) {
                ph = B1h + brow * (size_t)ldb1 + kt * 32 + kq;
                pl = B1l + brow * (size_t)ldb1 + kt * 32 + kq;
            } else {
                ph = B2h + brow * HH + (size_t)(kt - C1) * 32 + kq;
                pl = B2l + brow * HH + (size_t)(kt - C1) * 32 + kq;
            }
            rBh[i] = *(const short8*)ph;
            rBl[i] = *(const short8*)pl;
        }
    }

    // ---- staging constants: 2 x 16B per thread per chunk (16 KB/buffer) ----
    // tile (half,hl): 64 rows x 32k u16; row = 64B; 16B-slot XOR swizzle.
    int r_[2], ks_[2], hl_[2], half_[2], loff_[2];
#pragma unroll
    for (int q = 0; q < 2; ++q) {
        const int idx  = q * 512 + tid;
        const int tile = idx >> 8;          // 0..3 = half*2 + hilo
        half_[q] = tile >> 1;
        hl_[q]   = tile & 1;
        const int t8 = idx & 255;
        const int r  = t8 >> 2;
        const int k3 = t8 & 3;
        r_[q]  = r;
        ks_[q] = k3 * 8;                    // global k sub-offset (unswizzled)
        loff_[q] = tile * 2048 + r * 32 + ((k3 ^ ((r >> 1) & 3)) * 8);
    }

    // ---- A-frag read offsets (swizzled; row = mt*16 + cR, mt*16 keeps swizzle) ----
    const int cR = lane & 15, q4 = lane >> 4;
    const int abase = kh * 4096 + cR * 32 + ((q4 ^ ((cR >> 1) & 3)) * 8);

    // ---- epilogue constants ----
    const int jj  = j0 + (tid & 15);
    const int mb2 = (tid >> 4) * 2;
    const float bI = pbi[jj] + pbh[jj];
    const float bF = pbi[HH + jj] + pbh[HH + jj];
    const float bG = pbi[2 * HH + jj] + pbh[2 * HH + jj];
    const float bO = pbi[3 * HH + jj] + pbh[3 * HH + jj];
    float cst0 = 0.f, cst1 = 0.f;           // c-state in registers

    for (int n = 0; n <= TLEN; ++n) {
        const int rb = n & 1;
        const bool active = ROLE1 ? (n > 0) : (n < TLEN);
        if (active) {
            const u16 *A1h_, *A1l_, *A2h_, *A2l_;
            u16 *wh, *wl;
            size_t ld1;
            if (ROLE1) {
                A1h_ = rb ? h0hB : h0hA; A1l_ = rb ? h0lB : h0lA;
                A2h_ = rb ? h1hB : h1hA; A2l_ = rb ? h1lB : h1lA;
                wh   = rb ? h1hA : h1hB; wl   = rb ? h1lA : h1lB;
                ld1 = HH;
            } else {
                A1h_ = X1h + (size_t)n * DD; A1l_ = X1l + (size_t)n * DD;
                A2h_ = rb ? h0hB : h0hA;     A2l_ = rb ? h0lB : h0lA;
                wh   = rb ? h0hA : h0hB;     wl   = rb ? h0lA : h0lB;
                ld1 = (size_t)TLEN * DD;
            }

            auto srcp = [&](int kt, int r, int ks, int lo) -> const u16* {
                if (kt < C1) return (lo ? A1l_ : A1h_) + (size_t)(m0 + r) * ld1 + kt * 32 + ks;
                return (lo ? A2l_ : A2h_) + (size_t)(m0 + r) * HH + (size_t)(kt - C1) * 32 + ks;
            };

            float4v acc[4];
#pragma unroll
            for (int mt = 0; mt < 4; ++mt) acc[mt] = (float4v){0.f, 0.f, 0.f, 0.f};

            // ---- depth-2 prefetch pipeline; chunk c lives in reg-set c&1 ----
            short8 vS[2][2];
            vS[0][0] = *(const short8*)srcp(half_[0] * NKT + 0, r_[0], ks_[0], hl_[0]);
            vS[0][1] = *(const short8*)srcp(half_[1] * NKT + 0, r_[1], ks_[1], hl_[1]);
            if (NKT > 1) {
                vS[1][0] = *(const short8*)srcp(half_[0] * NKT + 1, r_[0], ks_[0], hl_[0]);
                vS[1][1] = *(const short8*)srcp(half_[1] * NKT + 1, r_[1], ks_[1], hl_[1]);
            }
            *(short8*)&smem[loff_[0]] = vS[0][0];   // stage chunk 0 -> buf0
            *(short8*)&smem[loff_[1]] = vS[0][1];

#pragma unroll
            for (int i = 0; i < NKT; ++i) {
                __syncthreads();               // buf[i&1] staged; prev reads done
                const int buf = i & 1;
                if (i + 1 < NKT) {             // stage chunk i+1 into buf^1
                    *(short8*)&smem[(buf ^ 1) * 8192 + loff_[0]] = vS[(i + 1) & 1][0];
                    *(short8*)&smem[(buf ^ 1) * 8192 + loff_[1]] = vS[(i + 1) & 1][1];
                }
                if (i + 2 < NKT) {             // issue loads for chunk i+2
                    vS[i & 1][0] = *(const short8*)srcp(half_[0] * NKT + i + 2, r_[0], ks_[0], hl_[0]);
                    vS[i & 1][1] = *(const short8*)srcp(half_[1] * NKT + i + 2, r_[1], ks_[1], hl_[1]);
                }
                const int ab = buf * 8192 + abase;
                short8 aH[4], aL[4];
#pragma unroll
                for (int mt = 0; mt < 4; ++mt) {
                    aH[mt] = *(const short8*)&smem[ab + mt * 512];
                    aL[mt] = *(const short8*)&smem[ab + 2048 + mt * 512];
                }
#pragma unroll
                for (int mt = 0; mt < 4; ++mt) {
                    acc[mt] = __builtin_amdgcn_mfma_f32_16x16x32_bf16(aH[mt], rBh[i], acc[mt], 0, 0, 0);
                    acc[mt] = __builtin_amdgcn_mfma_f32_16x16x32_bf16(aH[mt], rBl[i], acc[mt], 0, 0, 0);
                    acc[mt] = __builtin_amdgcn_mfma_f32_16x16x32_bf16(aL[mt], rBh[i], acc[mt], 0, 0, 0);
                }
            }

            // ---- gate/k-half exchange via LDS ----
            __syncthreads();
#pragma unroll
            for (int mt = 0; mt < 4; ++mt)
#pragma unroll
                for (int r = 0; r < 4; ++r)
                    sX[wv * 1152 + (mt * 16 + (lane >> 4) * 4 + r) * 18 + (lane & 15)] = acc[mt][r];
            __syncthreads();

#pragma unroll
            for (int p = 0; p < 2; ++p) {
                const int m = mb2 + p;
                const int xb = m * 18 + (tid & 15);
                const float gi = sX[0 * 1152 + xb] + sX[4 * 1152 + xb] + bI;
                const float gf = sX[1 * 1152 + xb] + sX[5 * 1152 + xb] + bF;
                const float gg = sX[2 * 1152 + xb] + sX[6 * 1152 + xb] + bG;
                const float go = sX[3 * 1152 + xb] + sX[7 * 1152 + xb] + bO;
                const float cp = p ? cst1 : cst0;
                const float cn = sigm(gf) * cp + sigm(gi) * tanhf(gg);
                const float h  = sigm(go) * tanhf(cn);
                if (p) cst1 = cn; else cst0 = cn;
                const size_t off = (size_t)(m0 + m) * HH + jj;
                const u16 hv = bf16rn(h);
                wh[off] = hv;
                wl[off] = bf16rn(h - bf16tf(hv));
                if (ROLE1 && n == TLEN) h1last[off] = h;
            }
        }

        // ---- m-group barrier: round-2 protocol, verbatim (proven to run) ----
        __syncthreads();   // drains vmcnt(0): h stores are in L2 before release
        if (tid == 0) {
            const unsigned g0 = __hip_atomic_load(bgen, __ATOMIC_RELAXED, __HIP_MEMORY_SCOPE_AGENT);
            const unsigned a = __hip_atomic_fetch_add(bcnt, 1u, __ATOMIC_RELEASE, __HIP_MEMORY_SCOPE_AGENT);
            if (a == 63u) {
                __hip_atomic_store(bcnt, 0u, __ATOMIC_RELAXED, __HIP_MEMORY_SCOPE_AGENT);
                __hip_atomic_store(bgen, g0 + 1u, __ATOMIC_RELEASE, __HIP_MEMORY_SCOPE_AGENT);
            } else {
                int sp = 0;
                while (__hip_atomic_load(bgen, __ATOMIC_RELAXED, __HIP_MEMORY_SCOPE_AGENT) == g0) {
                    __builtin_amdgcn_s_sleep(2);
                    if ((++sp & 63) == 0)   // safety net: periodic coherent-forcing poll
                        (void)__hip_atomic_load(bgen, __ATOMIC_ACQUIRE, __HIP_MEMORY_SCOPE_AGENT);
                }
            }
            // single acquire: L1/L2 fresh for next step's h reads (B is in regs,
            // so the invalidate no longer costs a weight refetch).
            (void)__hip_atomic_load(bgen, __ATOMIC_ACQUIRE, __HIP_MEMORY_SCOPE_AGENT);
        }
        __syncthreads();
    }
}

__global__ __launch_bounds__(512, 2) void lstm_persistent(
    const u16* __restrict__ xhi, const u16* __restrict__ xlo,
    const u16* __restrict__ Wih0h, const u16* __restrict__ Wih0l,
    const u16* __restrict__ Whh0h, const u16* __restrict__ Whh0l,
    const u16* __restrict__ Wih1h, const u16* __restrict__ Wih1l,
    const u16* __restrict__ Whh1h, const u16* __restrict__ Whh1l,
    const float* __restrict__ bi0, const float* __restrict__ bh0,
    const float* __restrict__ bi1, const float* __restrict__ bh1,
    u16* h0hA, u16* h0lA, u16* h0hB, u16* h0lB,
    u16* h1hA, u16* h1lA, u16* h1hB, u16* h1lB,
    float* __restrict__ h1last, unsigned* bar)
{
    __shared__ u16 smem[18432];   // 32KB staging (2 bufs) / 36.9KB exchange (aliased)
    const bool role1 = (blockIdx.x >= 128);
    const int idx = blockIdx.x & 127;
    const int m0 = (idx & 3) * 64;
    const int j0 = (idx >> 2) * 16;
    const int gid = idx & 3;
    unsigned* bcnt = bar + gid * 64;
    unsigned* bgen = bar + gid * 64 + 32;

    if (role1)
        lstm_body<16, 16, true>(nullptr, nullptr,
            Wih1h, Wih1l, HH, Whh1h, Whh1l, bi1, bh1,
            h0hA, h0lA, h0hB, h0lB, h1hA, h1lA, h1hB, h1lB,
            h1last, bcnt, bgen, m0, j0, smem);
    else
        lstm_body<9, 2, false>(xhi, xlo,
            Wih0h, Wih0l, DD, Whh0h, Whh0l, bi0, bh0,
            h0hA, h0lA, h0hB, h0lB, h1hA, h1lA, h1hB, h1lB,
            nullptr, bcnt, bgen, m0, j0, smem);
}

// ---------------- FC head (fp32, proven) ----------------

template <int MODE>
__global__ __launch_bounds__(256) void gemm_step(
    const float* __restrict__ A1, int lda1, int K1, const float* __restrict__ W1,
    const float* __restrict__ A2, int K2, const float* __restrict__ W2,
    const float* __restrict__ b1, const float* __restrict__ b2,
    const float* __restrict__ c_in, float* __restrict__ c_out,
    float* __restrict__ h_out)
{
    __shared__ float sA[16][33];
    __shared__ float sW[128][33];

    const int tid = threadIdx.x;
    const int tj  = tid & 31;
    const int tg  = tid >> 5;
    const int m0  = blockIdx.x * 16;
    const int j0  = blockIdx.y * ((MODE == 0) ? 32 : 128);

    float acc[2][4] = {{0.f, 0.f, 0.f, 0.f}, {0.f, 0.f, 0.f, 0.f}};

    for (int seg = 0; seg < 2; ++seg) {
        const float* A  = seg ? A2 : A1;
        const float* W  = seg ? W2 : W1;
        const int    K  = seg ? K2 : K1;
        const int    ld = seg ? HH : lda1;
        if (K == 0) continue;
        for (int kb = 0; kb < K; kb += 32) {
            __syncthreads();
            {
                int idxq = tid;
#pragma unroll
                for (int r = 0; r < 2; ++r, idxq += 256) {
                    int row = idxq >> 5, col = idxq & 31;
                    sA[row][col] = A[(m0 + row) * ld + kb + col];
                }
            }
            {
#pragma unroll
                for (int i = 0; i < 16; ++i) {
                    int idxq = i * 256 + tid;
                    int row = idxq >> 5, col = idxq & 31;
                    int grw;
                    if (MODE == 0) grw = (row >> 5) * HH + j0 + (row & 31);
                    else           grw = j0 + row;
                    sW[row][col] = W[grw * K + kb + col];
                }
            }
            __syncthreads();
#pragma unroll
            for (int k = 0; k < 32; ++k) {
                float a0 = sA[tg][k];
                float a1 = sA[tg + 8][k];
                float w0 = sW[tj][k];
                float w1 = sW[32 + tj][k];
                float w2 = sW[64 + tj][k];
                float w3 = sW[96 + tj][k];
                acc[0][0] += a0 * w0; acc[0][1] += a0 * w1;
                acc[0][2] += a0 * w2; acc[0][3] += a0 * w3;
                acc[1][0] += a1 * w0; acc[1][1] += a1 * w1;
                acc[1][2] += a1 * w2; acc[1][3] += a1 * w3;
            }
        }
    }

    if (MODE == 0) {
        const int j = j0 + tj;
        const float bi = b1[j] + b2[j];
        const float bf = b1[HH + j] + b2[HH + j];
        const float bg = b1[2 * HH + j] + b2[2 * HH + j];
        const float bo = b1[3 * HH + j] + b2[3 * HH + j];
#pragma unroll
        for (int r = 0; r < 2; ++r) {
            int m = m0 + tg + r * 8;
            float gi = acc[r][0] + bi;
            float gf = acc[r][1] + bf;
            float gg = acc[r][2] + bg;
            float go = acc[r][3] + bo;
            float cp = c_in[m * HH + j];
            float c  = sigm(gf) * cp + sigm(gi) * tanhf(gg);
            float h  = sigm(go) * tanhf(c);
            c_out[m * HH + j] = c;
            h_out[m * HH + j] = h;
        }
    } else {
#pragma unroll
        for (int r = 0; r < 2; ++r) {
            int m = m0 + tg + r * 8;
#pragma unroll
            for (int q = 0; q < 4; ++q) {
                int nn = j0 + q * 32 + tj;
                float v = acc[r][q] + b1[nn];
                h_out[m * HH + nn] = fmaxf(v, 0.f);
            }
        }
    }
}

__global__ __launch_bounds__(64) void fc2_kernel(
    const float* __restrict__ z, const float* __restrict__ W,
    const float* __restrict__ b, float* __restrict__ out)
{
    int m = blockIdx.x;
    int lane = threadIdx.x;
    float zr[8];
#pragma unroll
    for (int u = 0; u < 8; ++u) zr[u] = z[m * 512 + u * 64 + lane];
#pragma unroll
    for (int o = 0; o < 8; ++o) {
        float s = 0.f;
#pragma unroll
        for (int u = 0; u < 8; ++u) s += zr[u] * W[o * 512 + u * 64 + lane];
#pragma unroll
        for (int off = 32; off > 0; off >>= 1) s += __shfl_down(s, off);
        if (lane == 0) out[m * 8 + o] = s + b[o];
    }
}

__global__ __launch_bounds__(256) void zero_f_kernel(float* p, int n)
{
    int i = blockIdx.x * 256 + threadIdx.x;
    if (i < n) p[i] = 0.f;
}

// ---------------- host ----------------

extern "C" void kernel_launch(void* const* d_in, const int* in_sizes, int n_in,
                              void* d_out, int out_size, void* d_ws, size_t ws_size,
                              hipStream_t stream)
{
    const float* x     = (const float*)d_in[0];
    const float* W_ih0 = (const float*)d_in[1];
    const float* W_hh0 = (const float*)d_in[2];
    const float* b_ih0 = (const float*)d_in[3];
    const float* b_hh0 = (const float*)d_in[4];
    const float* W_ih1 = (const float*)d_in[5];
    const float* W_hh1 = (const float*)d_in[6];
    const float* b_ih1 = (const float*)d_in[7];
    const float* b_hh1 = (const float*)d_in[8];
    const float* W_fc1 = (const float*)d_in[9];
    const float* b_fc1 = (const float*)d_in[10];
    const float* W_fc2 = (const float*)d_in[11];
    const float* b_fc2 = (const float*)d_in[12];
    float* out = (float*)d_out;

    const size_t S  = (size_t)BB * HH;        // 131072 elems
    const size_t SB = S * sizeof(u16);        // 262144 B
    const size_t SF = S * sizeof(float);      // 524288 B
    const size_t XN = (size_t)BB * TLEN * DD; // 8388608

    const size_t NEED = 2097152 + 1024 /*zero region incl. barriers*/ +
                        4 * SB /*other h bufs*/ +
                        2 * SF /*h1last,zfc*/ + 2 * XN * 2 /*x split*/ +
                        2 * 131072 * 2 /*Wih0*/ + 3 * 2 * 1048576 * 2 /*Whh0,Wih1,Whh1*/;

    if (ws_size >= NEED) {
        char* W = (char*)d_ws;
        size_t o = 0;
        u16 *h0hi[2], *h0lo[2], *h1hi[2], *h1lo[2];
        // zero region first (2 MB + 1 KB): initial-parity h bufs, pad, barriers
        h0hi[0] = (u16*)(W + o); o += SB;
        h0lo[0] = (u16*)(W + o); o += SB;
        h1hi[1] = (u16*)(W + o); o += SB;
        h1lo[1] = (u16*)(W + o); o += SB;
        float* pad0 = (float*)(W + o); o += SF;   // kept for layout stability
        float* pad1 = (float*)(W + o); o += SF;
        unsigned* bar = (unsigned*)(W + o); o += 1024;   // 4 groups x (cnt,gen)
        (void)pad0; (void)pad1;
        // rest
        h0hi[1] = (u16*)(W + o); o += SB;
        h0lo[1] = (u16*)(W + o); o += SB;
        h1hi[0] = (u16*)(W + o); o += SB;
        h1lo[0] = (u16*)(W + o); o += SB;
        float* h1last = (float*)(W + o); o += SF;
        float* zfc    = (float*)(W + o); o += SF;
        u16* xhi = (u16*)(W + o); o += XN * 2;
        u16* xlo = (u16*)(W + o); o += XN * 2;
        u16* wih0h = (u16*)(W + o); o += 131072 * 2;
        u16* wih0l = (u16*)(W + o); o += 131072 * 2;
        u16* whh0h = (u16*)(W + o); o += 1048576 * 2;
        u16* whh0l = (u16*)(W + o); o += 1048576 * 2;
        u16* wih1h = (u16*)(W + o); o += 1048576 * 2;
        u16* wih1l = (u16*)(W + o); o += 1048576 * 2;
        u16* whh1h = (u16*)(W + o); o += 1048576 * 2;
        u16* whh1l = (u16*)(W + o); o += 1048576 * 2;

        // zero-init: 2 MB + 1 KB = 524544 u32
        zero_kernel<<<2049, 256, 0, stream>>>((unsigned*)d_ws, 524544);
        // splits
        split_kernel<<<2048, 256, 0, stream>>>(x, xhi, xlo, (int)XN);
        split_kernel<<<512, 256, 0, stream>>>(W_ih0, wih0h, wih0l, 131072);
        split_kernel<<<2048, 256, 0, stream>>>(W_hh0, whh0h, whh0l, 1048576);
        split_kernel<<<2048, 256, 0, stream>>>(W_ih1, wih1h, wih1l, 1048576);
        split_kernel<<<2048, 256, 0, stream>>>(W_hh1, whh1h, whh1l, 1048576);

        lstm_persistent<<<256, 512, 0, stream>>>(
            xhi, xlo,
            wih0h, wih0l, whh0h, whh0l,
            wih1h, wih1l, whh1h, whh1l,
            b_ih0, b_hh0, b_ih1, b_hh1,
            h0hi[0], h0lo[0], h0hi[1], h0lo[1],
            h1hi[0], h1lo[0], h1hi[1], h1lo[1],
            h1last, bar);

        dim3 grid_fc1(BB / 16, 512 / 128);
        gemm_step<1><<<grid_fc1, 256, 0, stream>>>(
            h1last, HH, HH, W_fc1, nullptr, 0, nullptr,
            b_fc1, nullptr, nullptr, nullptr, zfc);
        fc2_kernel<<<BB, 64, 0, stream>>>(zfc, W_fc2, b_fc2, out);
        return;
    }

    // -------- fallback: fp32 path (needs ~3.7 MB ws) --------
    float* wsf = (float*)d_ws;
    float* h0a = wsf + 0 * S;
    float* c0  = wsf + 1 * S;
    float* h1a = wsf + 2 * S;
    float* c1  = wsf + 3 * S;
    float* h0b = wsf + 4 * S;
    float* h1b = wsf + 5 * S;
    float* zb  = wsf + 6 * S;
    float* h0buf[2] = {h0a, h0b};
    float* h1buf[2] = {h1a, h1b};

    zero_f_kernel<<<(int)((4 * S + 255) / 256), 256, 0, stream>>>(wsf, (int)(4 * S));

    dim3 grid_lstm(BB / 16, HH / 32);
    for (int t = 0; t < TLEN; ++t) {
        const float* xt = x + (size_t)t * DD;
        gemm_step<0><<<grid_lstm, 256, 0, stream>>>(
            xt, TLEN * DD, DD, W_ih0,
            h0buf[t & 1], HH, W_hh0,
            b_ih0, b_hh0, c0, c0, h0buf[(t + 1) & 1]);
        gemm_step<0><<<grid_lstm, 256, 0, stream>>>(
            h0buf[(t + 1) & 1], HH, HH, W_ih1,
            h1buf[t & 1], HH, W_hh1,
            b_ih1, b_hh1, c1, c1, h1buf[(t + 1) & 1]);
    }
    dim3 grid_fc1(BB / 16, 512 / 128);
    gemm_step<1><<<grid_fc1, 256, 0, stream>>>(
        h1buf[0], HH, HH, W_fc1, nullptr, 0, nullptr,
        b_fc1, nullptr, nullptr, nullptr, zb);
    fc2_kernel<<<BB, 64, 0, stream>>>(zb, W_fc2, b_fc2, out);
}